// Round 3
// baseline (44.958 us; speedup 1.0000x reference)
//
#include <hip/hip_runtime.h>
#include <stdint.h>

typedef unsigned short u16;
typedef __attribute__((ext_vector_type(4))) u16    u16x4;
typedef __attribute__((ext_vector_type(8))) u16    u16x8;
typedef __attribute__((ext_vector_type(4))) float  f32x4;
typedef __attribute__((ext_vector_type(8))) __bf16 bf16x8;

__device__ __forceinline__ u16 f2bf(float f) {
    union { float f; uint32_t u; } v; v.f = f;
    uint32_t u = v.u;
    uint32_t rb = 0x7FFFu + ((u >> 16) & 1u);
    return (u16)((u + rb) >> 16);
}

__device__ __forceinline__ bf16x8 cvt8(f32x4 a, f32x4 b) {
    bf16x8 r;
    r[0] = (__bf16)a.x; r[1] = (__bf16)a.y; r[2] = (__bf16)a.z; r[3] = (__bf16)a.w;
    r[4] = (__bf16)b.x; r[5] = (__bf16)b.y; r[6] = (__bf16)b.z; r[7] = (__bf16)b.w;
    return r;
}

// ---------------- kernel 0: W[k][f] -> Wt[f][k] bf16 ----------------
__global__ __launch_bounds__(256) void gcn_wt(const float* __restrict__ W,
                                              u16* __restrict__ Wt) {
    int idx = blockIdx.x * 256 + threadIdx.x;   // 0..16383
    int k = idx >> 7, f = idx & 127;
    Wt[f * 128 + k] = f2bf(W[idx]);
}

// ---------------- kernel 1: hT[b][f][n] = bf16((x@W)^T + b) ----------------
__global__ __launch_bounds__(256) void gcn_xw(const float* __restrict__ x,
                                              const u16* __restrict__ Wt,
                                              const float* __restrict__ bias,
                                              u16* __restrict__ hT) {
    __shared__ u16 Wl[128 * 128];   // [f][k] swizzled (256B rows)
    __shared__ u16 Xl[128 * 128];   // [n][k] swizzled (256B rows)
    const int t  = threadIdx.x;
    const int bb = blockIdx.x >> 3;
    const int n0 = (blockIdx.x & 7) << 7;

#pragma unroll
    for (int i = 0; i < 16; ++i) {
        int o  = i * 256 + t;          // 8B chunk index, 0..4095
        int f  = o >> 5;
        int kb = (o & 31) * 8;
        u16x4 v = *(const u16x4*)((const char*)Wt + o * 8);
        *(u16x4*)((char*)Wl + f * 256 + (kb ^ ((f & 7) << 4))) = v;
    }
    const float* xb = x + (size_t)bb * (1024 * 128) + (size_t)n0 * 128;
#pragma unroll
    for (int i = 0; i < 16; ++i) {
        int o4 = i * 256 + t;
        int n  = o4 >> 5;
        int kb = (o4 & 31) * 8;
        f32x4 v = *(const f32x4*)(xb + (size_t)o4 * 4);
        u16x4 h; h.x = f2bf(v.x); h.y = f2bf(v.y); h.z = f2bf(v.z); h.w = f2bf(v.w);
        *(u16x4*)((char*)Xl + n * 256 + (kb ^ ((n & 7) << 4))) = h;
    }
    __syncthreads();

    const int w = t >> 6, l = t & 63;
    const int wr = w >> 1, wc = w & 1;
    f32x4 acc[4][4] = {};
#pragma unroll
    for (int kk = 0; kk < 4; ++kk) {
        const int kbyte = kk * 64 + (l >> 4) * 16;
        bf16x8 a[4], b[4];
#pragma unroll
        for (int mf = 0; mf < 4; ++mf) {
            int fl = wr * 64 + mf * 16 + (l & 15);
            a[mf] = *(const bf16x8*)((const char*)Wl + fl * 256 + (kbyte ^ ((fl & 7) << 4)));
        }
#pragma unroll
        for (int nn = 0; nn < 4; ++nn) {
            int nl = wc * 64 + nn * 16 + (l & 15);
            b[nn] = *(const bf16x8*)((const char*)Xl + nl * 256 + (kbyte ^ ((nl & 7) << 4)));
        }
#pragma unroll
        for (int mf = 0; mf < 4; ++mf)
#pragma unroll
            for (int nn = 0; nn < 4; ++nn)
                acc[mf][nn] = __builtin_amdgcn_mfma_f32_16x16x32_bf16(
                    a[mf], b[nn], acc[mf][nn], 0, 0, 0);
    }

    u16* ho = hT + (size_t)bb * 131072;
#pragma unroll
    for (int mf = 0; mf < 4; ++mf) {
        int fbase = wr * 64 + mf * 16 + (l >> 4) * 4;
#pragma unroll
        for (int r = 0; r < 4; ++r) {
            float bv = bias[fbase + r];
#pragma unroll
            for (int nn = 0; nn < 4; ++nn) {
                int n = wc * 64 + nn * 16 + (l & 15);
                ho[(size_t)(fbase + r) * 1024 + n0 + n] = f2bf(acc[mf][nn][r] + bv);
            }
        }
    }
}

// ---------------- kernel 2: out = relu(adj @ h + x) ----------------
// BM=64, BN=128, BK=64. Double-buffered global_load_lds pipeline.
// adj staged fp32 (convert at fragment read); hT staged bf16.
// Linear LDS dest + inverse-swizzled global source + swizzled ds_read.
__global__ __launch_bounds__(256) void gcn_agg(const float* __restrict__ adj,
                                               const u16* __restrict__ hT,
                                               const float* __restrict__ x,
                                               float* __restrict__ out) {
    __shared__ float Al[2][64 * 64];    // fp32, rows 256B, chunk-XOR swizzle
    __shared__ u16   Bl[2][128 * 64];   // bf16, rows 128B, chunk-XOR swizzle

    const int t = threadIdx.x;
    // bijective XCD swizzle: 512 blocks, 64 per XCD; one XCD owns 4 batches
    const int L  = (blockIdx.x & 7) * 64 + (blockIdx.x >> 3);
    const int bb = L >> 4;
    const int r0 = (L & 15) << 6;

    const float* adjb = adj + (size_t)bb * 1048576 + (size_t)r0 * 1024;
    const u16*   hTb  = hT + (size_t)bb * 131072;

    const int w = t >> 6, l = t & 63;
    const int wr = w >> 1, wc = w & 1;      // wave: 32 rows x 64 f

    // Pre-swizzled global sources. LDS chunk c = (w*4+i)*64 + lane (16B units).
    // A: row r = c>>4, swz col-byte cb = ((c&15)*16) ^ ((r&7)<<4)
    // B: row f = c>>3, swz col-byte cb = ((c&7)*16)  ^ ((f&7)<<4)
    const float* srcA[4];
    const u16*   srcB[4];
#pragma unroll
    for (int i = 0; i < 4; ++i) {
        int c  = (w * 4 + i) * 64 + l;
        int rA = c >> 4, cbA = ((c & 15) * 16) ^ ((rA & 7) << 4);
        srcA[i] = adjb + (size_t)rA * 1024 + (cbA >> 2);
        int fB = c >> 3, cbB = ((c & 7) * 16) ^ ((fB & 7) << 4);
        srcB[i] = hTb + (size_t)fB * 1024 + (cbB >> 1);
    }

#define STAGE(buf, ks)                                                          \
    do {                                                                        \
        const int k0 = (ks) * 64;                                               \
        _Pragma("unroll")                                                       \
        for (int i = 0; i < 4; ++i) {                                           \
            __builtin_amdgcn_global_load_lds(                                   \
                (const __attribute__((address_space(1))) void*)(srcA[i] + k0),  \
                (__attribute__((address_space(3))) void*)((char*)&Al[buf][0] + (w * 4 + i) * 1024), \
                16, 0, 0);                                                      \
            __builtin_amdgcn_global_load_lds(                                   \
                (const __attribute__((address_space(1))) void*)(srcB[i] + k0),  \
                (__attribute__((address_space(3))) void*)((char*)&Bl[buf][0] + (w * 4 + i) * 1024), \
                16, 0, 0);                                                      \
        }                                                                       \
    } while (0)

#define COMPUTE(buf)                                                            \
    do {                                                                        \
        _Pragma("unroll")                                                       \
        for (int kk = 0; kk < 2; ++kk) {                                        \
            const int ke = kk * 32 + (l >> 4) * 8;                              \
            bf16x8 a[2], b[4];                                                  \
            _Pragma("unroll")                                                   \
            for (int mf = 0; mf < 2; ++mf) {                                    \
                int rl  = wr * 32 + mf * 16 + (l & 15);                         \
                int cb0 = (ke * 4) ^ ((rl & 7) << 4);                           \
                int cb1 = (ke * 4 + 16) ^ ((rl & 7) << 4);                      \
                f32x4 lo = *(const f32x4*)((const char*)&Al[buf][0] + rl * 256 + cb0); \
                f32x4 hi = *(const f32x4*)((const char*)&Al[buf][0] + rl * 256 + cb1); \
                a[mf] = cvt8(lo, hi);                                           \
            }                                                                   \
            _Pragma("unroll")                                                   \
            for (int nn = 0; nn < 4; ++nn) {                                    \
                int fl = wc * 64 + nn * 16 + (l & 15);                          \
                int cb = (ke * 2) ^ ((fl & 7) << 4);                            \
                b[nn] = *(const bf16x8*)((const char*)&Bl[buf][0] + fl * 128 + cb); \
            }                                                                   \
            _Pragma("unroll")                                                   \
            for (int mf = 0; mf < 2; ++mf)                                      \
                _Pragma("unroll")                                               \
                for (int nn = 0; nn < 4; ++nn)                                  \
                    acc[mf][nn] = __builtin_amdgcn_mfma_f32_16x16x32_bf16(      \
                        a[mf], b[nn], acc[mf][nn], 0, 0, 0);                    \
        }                                                                       \
    } while (0)

    f32x4 acc[2][4] = {};

    STAGE(0, 0);
    __syncthreads();
    for (int ks = 0; ks < 16; ks += 2) {
        STAGE(1, ks + 1);
        COMPUTE(0);
        __syncthreads();
        if (ks + 2 < 16) STAGE(0, ks + 2);
        COMPUTE(1);
        __syncthreads();
    }
#undef STAGE
#undef COMPUTE

    // epilogue: + x, relu, fp32 store
    const float* xb = x + (size_t)bb * 131072;
    float*       ob = out + (size_t)bb * 131072;
#pragma unroll
    for (int mf = 0; mf < 2; ++mf) {
#pragma unroll
        for (int j = 0; j < 4; ++j) {
            int r = r0 + wr * 32 + mf * 16 + (l >> 4) * 4 + j;
#pragma unroll
            for (int nn = 0; nn < 4; ++nn) {
                int f = wc * 64 + nn * 16 + (l & 15);
                size_t idx = (size_t)r * 128 + f;
                float v = acc[mf][nn][j] + xb[idx];
                ob[idx] = fmaxf(v, 0.0f);
            }
        }
    }
}

extern "C" void kernel_launch(void* const* d_in, const int* in_sizes, int n_in,
                              void* d_out, int out_size, void* d_ws, size_t ws_size,
                              hipStream_t stream) {
    const float* x    = (const float*)d_in[0];
    const float* adj  = (const float*)d_in[1];
    const float* W    = (const float*)d_in[2];
    const float* bias = (const float*)d_in[3];
    float* out = (float*)d_out;

    u16* hT = (u16*)d_ws;                                    // 8 MiB
    u16* Wt = (u16*)((char*)d_ws + (size_t)32 * 131072 * 2); // +32 KiB

    gcn_wt <<<dim3(64),  dim3(256), 0, stream>>>(W, Wt);
    gcn_xw <<<dim3(256), dim3(256), 0, stream>>>(x, Wt, bias, hT);
    gcn_agg<<<dim3(512), dim3(256), 0, stream>>>(adj, hT, x, out);
}

// Round 4
// 40.893 us; speedup vs baseline: 1.0994x; 1.0994x over previous
//
#include <hip/hip_runtime.h>
#include <stdint.h>

typedef unsigned short u16;
typedef __attribute__((ext_vector_type(4))) u16    u16x4;
typedef __attribute__((ext_vector_type(8))) u16    u16x8;
typedef __attribute__((ext_vector_type(4))) float  f32x4;
typedef __attribute__((ext_vector_type(8))) __bf16 bf16x8;

__device__ __forceinline__ u16 f2bf(float f) {
    union { float f; uint32_t u; } v; v.f = f;
    uint32_t u = v.u;
    uint32_t rb = 0x7FFFu + ((u >> 16) & 1u);
    return (u16)((u + rb) >> 16);
}

// ---------------- kernel 0: W[k][f] -> Wt[f][k] bf16 ----------------
__global__ __launch_bounds__(256) void gcn_wt(const float* __restrict__ W,
                                              u16* __restrict__ Wt) {
    int idx = blockIdx.x * 256 + threadIdx.x;   // 0..16383
    int k = idx >> 7, f = idx & 127;
    Wt[f * 128 + k] = f2bf(W[idx]);
}

// ---------------- kernel 1: hT[b][f][n] = bf16((x@W)^T + b) ----------------
__global__ __launch_bounds__(256) void gcn_xw(const float* __restrict__ x,
                                              const u16* __restrict__ Wt,
                                              const float* __restrict__ bias,
                                              u16* __restrict__ hT) {
    __shared__ u16 Wl[128 * 128];   // [f][k] swizzled (256B rows)
    __shared__ u16 Xl[128 * 128];   // [n][k] swizzled (256B rows)
    const int t  = threadIdx.x;
    const int bb = blockIdx.x >> 3;
    const int n0 = (blockIdx.x & 7) << 7;

#pragma unroll
    for (int i = 0; i < 16; ++i) {
        int o  = i * 256 + t;          // 8B chunk index, 0..4095
        int f  = o >> 5;
        int kb = (o & 31) * 8;
        u16x4 v = *(const u16x4*)((const char*)Wt + o * 8);
        *(u16x4*)((char*)Wl + f * 256 + (kb ^ ((f & 7) << 4))) = v;
    }
    const float* xb = x + (size_t)bb * (1024 * 128) + (size_t)n0 * 128;
#pragma unroll
    for (int i = 0; i < 16; ++i) {
        int o4 = i * 256 + t;
        int n  = o4 >> 5;
        int kb = (o4 & 31) * 8;
        f32x4 v = *(const f32x4*)(xb + (size_t)o4 * 4);
        u16x4 h; h.x = f2bf(v.x); h.y = f2bf(v.y); h.z = f2bf(v.z); h.w = f2bf(v.w);
        *(u16x4*)((char*)Xl + n * 256 + (kb ^ ((n & 7) << 4))) = h;
    }
    __syncthreads();

    const int w = t >> 6, l = t & 63;
    const int wr = w >> 1, wc = w & 1;
    f32x4 acc[4][4] = {};
#pragma unroll
    for (int kk = 0; kk < 4; ++kk) {
        const int kbyte = kk * 64 + (l >> 4) * 16;
        bf16x8 a[4], b[4];
#pragma unroll
        for (int mf = 0; mf < 4; ++mf) {
            int fl = wr * 64 + mf * 16 + (l & 15);
            a[mf] = *(const bf16x8*)((const char*)Wl + fl * 256 + (kbyte ^ ((fl & 7) << 4)));
        }
#pragma unroll
        for (int nn = 0; nn < 4; ++nn) {
            int nl = wc * 64 + nn * 16 + (l & 15);
            b[nn] = *(const bf16x8*)((const char*)Xl + nl * 256 + (kbyte ^ ((nl & 7) << 4)));
        }
#pragma unroll
        for (int mf = 0; mf < 4; ++mf)
#pragma unroll
            for (int nn = 0; nn < 4; ++nn)
                acc[mf][nn] = __builtin_amdgcn_mfma_f32_16x16x32_bf16(
                    a[mf], b[nn], acc[mf][nn], 0, 0, 0);
    }

    u16* ho = hT + (size_t)bb * 131072;
#pragma unroll
    for (int mf = 0; mf < 4; ++mf) {
        int fbase = wr * 64 + mf * 16 + (l >> 4) * 4;
#pragma unroll
        for (int r = 0; r < 4; ++r) {
            float bv = bias[fbase + r];
#pragma unroll
            for (int nn = 0; nn < 4; ++nn) {
                int n = wc * 64 + nn * 16 + (l & 15);
                ho[(size_t)(fbase + r) * 1024 + n0 + n] = f2bf(acc[mf][nn][r] + bv);
            }
        }
    }
}

// ---------------- kernel 2: out = relu(adj @ h + x) ----------------
// BM=64, BN=128, BK=64. 512 threads (8 waves, wave tile 16x64).
// Reg-staged depth-2 prefetch, LDS double-buffer, ONE raw barrier per
// K-tile (lgkmcnt drain only — vmcnt stays in flight across barriers).
__global__ __launch_bounds__(512, 4) void gcn_agg(const float* __restrict__ adj,
                                                  const u16* __restrict__ hT,
                                                  const float* __restrict__ x,
                                                  float* __restrict__ out) {
    __shared__ u16 Al[2][64 * 64];      // bf16 adj tile, 8 KB each, swizzled
    __shared__ u16 Bl[2][128 * 64];     // bf16 hT tile, 16 KB each, swizzled

    const int t = threadIdx.x;          // 0..511
    // bijective XCD swizzle: 512 blocks, 64 per XCD; one XCD owns 4 batches
    const int L  = (blockIdx.x & 7) * 64 + (blockIdx.x >> 3);
    const int bb = L >> 4;
    const int r0 = (L & 15) << 6;

    const float* adjb = adj + (size_t)bb * 1048576 + (size_t)r0 * 1024;
    const u16*   hTb  = hT + (size_t)bb * 131072;

    const int w = t >> 6, l = t & 63;
    const int wr = w >> 1, wc = w & 1;  // 4x2 wave grid: 16 rows x 64 f each

    // Staging geometry (per thread, per K-tile):
    //  A: chunk c=t: row rA=t>>3, k8=t&7 -> 2x f32x4 global, 1x u16x8 LDS
    //  B: chunks t and t+512: rows fB0=t>>3, fB1=64+(t>>3), same k8
    const int rA  = t >> 3, k8 = t & 7;
    const float* gA  = adjb + (size_t)rA * 1024 + k8 * 8;
    const u16*   gB0 = hTb + (size_t)rA * 1024 + k8 * 8;          // fB0 == rA
    const u16*   gB1 = gB0 + 64 * 1024;
    const int ldsA  = rA * 128 + ((k8 * 16) ^ ((rA & 7) << 4));
    const int ldsB0 = rA * 128 + ((k8 * 16) ^ ((rA & 7) << 4));
    const int ldsB1 = (64 + rA) * 128 + ((k8 * 16) ^ ((rA & 7) << 4));

#define LOADT(ar, br, ks)                                   \
    do {                                                    \
        const int k0 = (ks) * 64;                           \
        ar[0] = *(const f32x4*)(gA + k0);                   \
        ar[1] = *(const f32x4*)(gA + k0 + 4);               \
        br[0] = *(const u16x8*)(gB0 + k0);                  \
        br[1] = *(const u16x8*)(gB1 + k0);                  \
    } while (0)

#define WRITET(buf, ar, br)                                 \
    do {                                                    \
        u16x8 ha;                                           \
        ha[0] = f2bf(ar[0].x); ha[1] = f2bf(ar[0].y);       \
        ha[2] = f2bf(ar[0].z); ha[3] = f2bf(ar[0].w);       \
        ha[4] = f2bf(ar[1].x); ha[5] = f2bf(ar[1].y);       \
        ha[6] = f2bf(ar[1].z); ha[7] = f2bf(ar[1].w);       \
        *(u16x8*)((char*)&Al[buf][0] + ldsA)  = ha;         \
        *(u16x8*)((char*)&Bl[buf][0] + ldsB0) = br[0];      \
        *(u16x8*)((char*)&Bl[buf][0] + ldsB1) = br[1];      \
    } while (0)

// lgkmcnt drain + barrier in ONE memory-clobbered asm: LDS writes are
// visible wave-wide at the barrier, but outstanding GLOBAL loads (vmcnt)
// are NOT drained — the prefetch survives the barrier.
#define BARRIER() asm volatile("s_waitcnt lgkmcnt(0)\ns_barrier" ::: "memory")

#define COMPUTE(buf)                                                            \
    do {                                                                        \
        _Pragma("unroll")                                                       \
        for (int kk = 0; kk < 2; ++kk) {                                        \
            const int kbyte = kk * 64 + (l >> 4) * 16;                          \
            const int rl = wr * 16 + (l & 15);                                  \
            bf16x8 a = *(const bf16x8*)((const char*)&Al[buf][0] + rl * 128 +   \
                                        (kbyte ^ ((rl & 7) << 4)));             \
            bf16x8 b[4];                                                        \
            _Pragma("unroll")                                                   \
            for (int nn = 0; nn < 4; ++nn) {                                    \
                int fl = wc * 64 + nn * 16 + (l & 15);                          \
                b[nn] = *(const bf16x8*)((const char*)&Bl[buf][0] + fl * 128 +  \
                                         (kbyte ^ ((fl & 7) << 4)));            \
            }                                                                   \
            _Pragma("unroll")                                                   \
            for (int nn = 0; nn < 4; ++nn)                                      \
                acc[nn] = __builtin_amdgcn_mfma_f32_16x16x32_bf16(              \
                    a, b[nn], acc[nn], 0, 0, 0);                                \
        }                                                                       \
    } while (0)

    f32x4 acc[4] = {};
    f32x4 a0[2], a1[2];
    u16x8 b0[2], b1[2];

    LOADT(a0, b0, 0);
    LOADT(a1, b1, 1);
#pragma unroll
    for (int ks = 0; ks < 16; ks += 2) {
        WRITET(0, a0, b0);
        BARRIER();
        if (ks + 2 < 16) LOADT(a0, b0, ks + 2);
        COMPUTE(0);
        WRITET(1, a1, b1);
        BARRIER();
        if (ks + 3 < 16) LOADT(a1, b1, ks + 3);
        COMPUTE(1);
    }
#undef LOADT
#undef WRITET
#undef BARRIER
#undef COMPUTE

    // epilogue: + x, relu, fp32 store
    const float* xb = x + (size_t)bb * 131072;
    float*       ob = out + (size_t)bb * 131072;
#pragma unroll
    for (int j = 0; j < 4; ++j) {
        int r = r0 + wr * 16 + (l >> 4) * 4 + j;
#pragma unroll
        for (int nn = 0; nn < 4; ++nn) {
            int f = wc * 64 + nn * 16 + (l & 15);
            size_t idx = (size_t)r * 128 + f;
            float v = acc[nn][j] + xb[idx];
            ob[idx] = fmaxf(v, 0.0f);
        }
    }
}

extern "C" void kernel_launch(void* const* d_in, const int* in_sizes, int n_in,
                              void* d_out, int out_size, void* d_ws, size_t ws_size,
                              hipStream_t stream) {
    const float* x    = (const float*)d_in[0];
    const float* adj  = (const float*)d_in[1];
    const float* W    = (const float*)d_in[2];
    const float* bias = (const float*)d_in[3];
    float* out = (float*)d_out;

    u16* hT = (u16*)d_ws;                                    // 8 MiB
    u16* Wt = (u16*)((char*)d_ws + (size_t)32 * 131072 * 2); // +32 KiB

    gcn_wt <<<dim3(64),  dim3(256), 0, stream>>>(W, Wt);
    gcn_xw <<<dim3(256), dim3(256), 0, stream>>>(x, Wt, bias, hT);
    gcn_agg<<<dim3(512), dim3(512), 0, stream>>>(adj, hT, x, out);
}